// Round 2
// baseline (2181.728 us; speedup 1.0000x reference)
//
#include <hip/hip_runtime.h>
#include <hip/hip_bf16.h>
#include <stdint.h>

#define N_PTS 16384
#define S_OUT 1024

// Inputs: float32. Outputs: float32.
// d_out = new_xyz f32[4*1024*3] ++ new_points f32[4*1024*128].
// d_ws  = knn indices int32[4*1024*32].
//
// sq-formula fingerprints vs harness np ref (output-1 absmax):
//   (sumq - 2*dot) + sumx, dot in {asc,desc} x {mul/add,FMA}: 0.19921875 (all)
//   true distance (f32-direct == f64-direct): 0.3359375
//   knn: classic PointNet square_distance association —
//   sq = (sumq + sumx) - 2*dot, dot = ascending FMA (np.matmul/BLAS k=3
//   micro-kernel: acc=rn(a0*b0); acc=fma(a1,b1,acc); acc=fma(a2,b2,acc)).

// ---------------------------------------------------------------------------
// Kernel 1: farthest point sampling (bit-exact vs np ref).
// Distance math UNCHANGED: f32 direct, mul/add ascending, fminf.
// ROUND 13: fit the forced 128-reg/wave unified budget instead of fighting it.
//  R12 evidence: VGPR 80 + AGPR 48 = exactly 128 -> 32-pt/thread arrays were
//  AGPR-resident, ~10 extra VALU ops/pt of v_accvgpr round-trips (22 vs 12).
//  - 1024 threads x 16 pts/thread: arrays = 64 regs + ~35 working < 128
//    -> true VGPR residency, zero AGPR traffic. Same total VALU work.
//  - 16 waves/CU doubles latency hiding on the reduce/broadcast tail.
//  - cross-wave reduce: lane-parallel -- every lane reads sred[lane&15]
//    (16 u64 = 32 banks exactly; lanes l and l+16 broadcast), then 4-step
//    shfl_xor u64-max butterfly (~20 ops vs 45-op linear scan), no extra
//    barrier. Tie semantics identical: key = (val bits << 32) | ~index.
//  - sred double-buffered -> ONE __syncthreads per iteration (write p,
//    barrier, read p; two barriers separate any re-write of buffer p).
// ---------------------------------------------------------------------------
__global__ __launch_bounds__(1024) void fps_kernel(
    const float* __restrict__ xyz,
    float* __restrict__ out_newxyz)
{
  const int b    = blockIdx.x;
  const int tid  = threadIdx.x;
  const int lane = tid & 63;
  const int wid  = tid >> 6;           // 16 waves
  const float* base = xyz + (size_t)b * N_PTS * 3;

  float px[16], py[16], pz[16], dist[16];
#pragma unroll
  for (int i = 0; i < 16; ++i) {
    int n = tid * 16 + i;
    px[i] = base[n * 3 + 0];
    py[i] = base[n * 3 + 1];
    pz[i] = base[n * 3 + 2];
    dist[i] = 1e10f;
  }

  __shared__ unsigned long long sred[2][16];

  float cx = base[0], cy = base[1], cz = base[2];

  for (int s = 0; s < S_OUT; ++s) {
    if (tid == 0) {
      size_t o = ((size_t)b * S_OUT + s) * 3;
      out_newxyz[o + 0] = cx;
      out_newxyz[o + 1] = cy;
      out_newxyz[o + 2] = cz;
    }
    if (s == S_OUT - 1) break;

    // ---- update distances, thread-local argmax (12 VALU ops/pt) ----
    float best  = -1.0f;   // dist values are >= +0, so -1 < everything
    int   bestI = 0;
#pragma unroll
    for (int i = 0; i < 16; ++i) {
      float dx = __fsub_rn(px[i], cx);
      float dy = __fsub_rn(py[i], cy);
      float dz = __fsub_rn(pz[i], cz);
      float dd = __fadd_rn(__fadd_rn(__fmul_rn(dx, dx), __fmul_rn(dy, dy)),
                           __fmul_rn(dz, dz));
      float dm = fminf(dist[i], dd);
      dist[i] = dm;
      bool c = dm > best;          // strict: first max kept -> lowest index
      best  = c ? dm : best;
      bestI = c ? i  : bestI;
    }
    const unsigned bestN = (unsigned)(tid * 16 + bestI);

    // ---- wave reduce: f32 max butterfly, then winner lane by ballot ----
    float m = best;
#pragma unroll
    for (int off = 1; off < 64; off <<= 1)
      m = fmaxf(m, __shfl_xor(m, off));
    // lanes own ascending index ranges: lowest matching lane == lowest index
    unsigned long long msk = __ballot(best == m);
    int wl = __ffsll(msk) - 1;
    unsigned wn = (unsigned)__shfl((int)bestN, wl);

    const int p = s & 1;           // double buffer: 1 barrier/iter is safe
    if (lane == 0)
      sred[p][wid] = ((unsigned long long)__float_as_uint(m) << 32) |
                     (unsigned long long)(0xFFFFFFFFu - wn);
    __syncthreads();

    // ---- block reduce: lane-parallel butterfly over the 16 wave keys ----
    unsigned long long k = sred[p][lane & 15];
#pragma unroll
    for (int off = 1; off < 16; off <<= 1) {
      unsigned long long o = __shfl_xor(k, off);
      if (o > k) k = o;
    }
    unsigned n = 0xFFFFFFFFu - (unsigned)(k & 0xFFFFFFFFull);
    n = __builtin_amdgcn_readfirstlane(n);
    const float* pc = base + (size_t)n * 3;
    cx = pc[0]; cy = pc[1]; cz = pc[2];
  }
}

// ---------------------------------------------------------------------------
// Kernel 2: exact 32-NN per centroid, two-level radix select. (UNCHANGED)
//   sq = (sumq + sumx) - 2*dot,  dot = ascending FMA (BLAS sgemm k=3).
// sumq/sumx stay mul/add ascending (np.sum ufunc, n=3 sequential).
// Keys: sign-aware order-preserving u32. Levels bits[31:21], [20:10];
// candidates (u<<32)|n; stable (key, idx) extraction.
// ---------------------------------------------------------------------------
__global__ __launch_bounds__(256, 2) void knn_kernel(
    const float* __restrict__ xyz,
    const float* __restrict__ newxyz,
    int* __restrict__ knn_out)
{
  const int bs  = blockIdx.x;        // b*1024 + s
  const int b   = bs >> 10;
  const int tid = threadIdx.x;
  const float* base = xyz + (size_t)b * N_PTS * 3;

  const float qx = newxyz[(size_t)bs * 3 + 0];
  const float qy = newxyz[(size_t)bs * 3 + 1];
  const float qz = newxyz[(size_t)bs * 3 + 2];
  const float sumq = __fadd_rn(__fadd_rn(__fmul_rn(qx, qx), __fmul_rn(qy, qy)),
                               __fmul_rn(qz, qz));

  __shared__ unsigned hist[2048];
  __shared__ unsigned tsum[256];
  __shared__ unsigned long long cand[512];
  __shared__ unsigned long long s_min;
  __shared__ int s_b1, s_r1, s_b2, s_r2, s_cntL, s_cntC;

  for (int i = tid; i < 2048; i += 256) hist[i] = 0;
  if (tid == 0) { s_cntL = 0; s_cntC = 0; }
  __syncthreads();

#define KNN_KEY(n, u)                                                          \
    float x = base[(n) * 3 + 0];                                               \
    float y = base[(n) * 3 + 1];                                               \
    float z = base[(n) * 3 + 2];                                               \
    float sumx = __fadd_rn(__fadd_rn(__fmul_rn(x, x), __fmul_rn(y, y)),        \
                           __fmul_rn(z, z));                                   \
    float dot  = __fmul_rn(qx, x);                                             \
    dot = fmaf(qy, y, dot);                                                    \
    dot = fmaf(qz, z, dot);                                                    \
    float sq   = __fsub_rn(__fadd_rn(sumq, sumx), __fmul_rn(2.0f, dot));       \
    unsigned u = __float_as_uint(sq);                                          \
    u ^= (u & 0x80000000u) ? 0xFFFFFFFFu : 0x80000000u;

  // pass 1: level-1 histogram (bits 31:21)
  for (int j = 0; j < 64; ++j) {
    int n = j * 256 + tid;
    KNN_KEY(n, u)
    atomicAdd(&hist[u >> 21], 1u);
  }
  __syncthreads();

  unsigned ts = 0;
#pragma unroll
  for (int u = 0; u < 8; ++u) ts += hist[tid * 8 + u];
  tsum[tid] = ts;
  __syncthreads();

  if (tid == 0) {       // find level-1 bin containing rank 32
    unsigned acc = 0; int t2 = 0;
    for (; t2 < 256; ++t2) { unsigned h = tsum[t2]; if (acc + h >= 32u) break; acc += h; }
    int u2 = t2 * 8;
    for (;; ++u2) { unsigned h = hist[u2]; if (acc + h >= 32u) break; acc += h; }
    s_b1 = u2; s_r1 = 32 - (int)acc;      // rank within bin b1, >= 1
  }
  __syncthreads();
  const unsigned b1 = (unsigned)s_b1;
  const int r1 = s_r1;

  // clear histogram for level 2
  for (int i = tid; i < 2048; i += 256) hist[i] = 0;
  __syncthreads();

  // pass 2: level-2 histogram (bits 20:10) of keys inside bin b1
  for (int j = 0; j < 64; ++j) {
    int n = j * 256 + tid;
    KNN_KEY(n, u)
    if ((u >> 21) == b1) atomicAdd(&hist[(u >> 10) & 0x7FFu], 1u);
  }
  __syncthreads();

  ts = 0;
#pragma unroll
  for (int u = 0; u < 8; ++u) ts += hist[tid * 8 + u];
  tsum[tid] = ts;
  __syncthreads();

  if (tid == 0) {       // find level-2 sub-bin containing rank r1
    unsigned acc = 0; int t2 = 0;
    for (; t2 < 256; ++t2) { unsigned h = tsum[t2]; if (acc + h >= (unsigned)r1) break; acc += h; }
    int u2 = t2 * 8;
    for (;; ++u2) { unsigned h = hist[u2]; if (acc + h >= (unsigned)r1) break; acc += h; }
    s_b2 = u2; s_r2 = r1 - (int)acc;      // rank within sub-bin b2, >= 1
  }
  __syncthreads();
  const unsigned b2 = (unsigned)s_b2;

  int* outp = knn_out + (size_t)bs * 32;

  // pass 3: emit below-(b1,b2) directly; exact 22-bit-prefix matches -> cand
  for (int j = 0; j < 64; ++j) {
    int n = j * 256 + tid;
    KNN_KEY(n, u)
    unsigned bin = u >> 21;
    if (bin < b1) {
      int p = atomicAdd(&s_cntL, 1);
      outp[p] = n;
    } else if (bin == b1) {
      unsigned sub = (u >> 10) & 0x7FFu;
      if (sub < b2) {
        int p = atomicAdd(&s_cntL, 1);
        outp[p] = n;
      } else if (sub == b2) {
        int p = atomicAdd(&s_cntC, 1);
        if (p < 512) cand[p] = ((unsigned long long)u << 32) | (unsigned)n;
      }
    }
  }
  __syncthreads();
#undef KNN_KEY

  const int r   = s_r2;
  const int cl  = s_cntL;             // == 32 - r
  const int cnt = min(s_cntC, 512);
  unsigned long long last = 0ull;
  for (int i = 0; i < r; ++i) {
    if (tid == 0) s_min = ~0ull;
    __syncthreads();
    for (int p = tid; p < cnt; p += 256) {
      unsigned long long v = cand[p];
      if (i == 0 ? 1 : (v > last)) atomicMin(&s_min, v);
    }
    __syncthreads();
    unsigned long long m = s_min;
    if (tid == 0) outp[cl + i] = (int)(unsigned)(m & 0xFFFFFFFFull);
    last = m;
    __syncthreads();
  }
}

// ---------------------------------------------------------------------------
// Kernel 3: fused gather + (dense+BN+ReLU)x3 + max over K. 2 centroids per
// block (256 threads = 2 groups x 128). All f32; weights staged per-layer in
// LDS. Gathered indices clamped to [0,16383] defensively. (UNCHANGED)
// ---------------------------------------------------------------------------
__global__ __launch_bounds__(256, 2) void mlp_kernel(
    const float* __restrict__ xyz,
    const float* __restrict__ points,
    const float* __restrict__ newxyz,
    const int* __restrict__ knn,
    const float* __restrict__ w0, const float* __restrict__ g0,
    const float* __restrict__ b0, const float* __restrict__ mm0,
    const float* __restrict__ mv0,
    const float* __restrict__ w1, const float* __restrict__ g1,
    const float* __restrict__ b1_, const float* __restrict__ mm1,
    const float* __restrict__ mv1,
    const float* __restrict__ w2, const float* __restrict__ g2,
    const float* __restrict__ b2_, const float* __restrict__ mm2,
    const float* __restrict__ mv2,
    float* __restrict__ out1)
{
  const int tid = threadIdx.x;
  const int BS0 = blockIdx.x * 2;

  __shared__ __align__(16) float xT[2][67][36];  // input feats (c-major); reused as a2
  __shared__ __align__(16) float a1[2][64][36];  // layer-1 out; reused as k-max partials
  __shared__ __align__(16) float wbuf[8192];     // current layer weights (f32)

  // ---- gather: x = [grouped_xyz - new_xyz (3) ; grouped_points (64)] ----
  {
    const int sg = tid >> 7;
    const int j  = (tid >> 2) & 31;
    const int cq = tid & 3;
    const int S  = BS0 + sg;
    const int bb = S >> 10;
    const int n  = knn[(size_t)S * 32 + j] & (N_PTS - 1);   // defensive clamp
    const float* pbase = points + ((size_t)bb * N_PTS + n) * 64;
    const float* xbase = xyz + ((size_t)bb * N_PTS + n) * 3;
    for (int c = cq; c < 67; c += 4) {
      float v;
      if (c < 3) v = __fsub_rn(xbase[c], newxyz[(size_t)S * 3 + c]);
      else       v = pbase[c - 3];
      xT[sg][c][j] = v;
    }
  }
  for (int i = tid; i < 67 * 64; i += 256) wbuf[i] = w0[i];
  __syncthreads();

  const int sg = tid >> 7;
  const int t  = tid & 127;

  // ---- layer 1: 67 -> 64 ----
  {
    const int ot = t & 15, kt = t >> 4;
    const int o0 = ot * 4, k0 = kt * 4;
    float acc[4][4] = {};
    for (int c = 0; c < 67; ++c) {
      float4 xv = *(const float4*)&xT[sg][c][k0];
      float4 wq = *(const float4*)&wbuf[c * 64 + o0];
      float wv[4] = { wq.x, wq.y, wq.z, wq.w };
      float xs[4] = { xv.x, xv.y, xv.z, xv.w };
#pragma unroll
      for (int a = 0; a < 4; ++a)
#pragma unroll
        for (int k2 = 0; k2 < 4; ++k2)
          acc[a][k2] = fmaf(wv[a], xs[k2], acc[a][k2]);
    }
#pragma unroll
    for (int jj = 0; jj < 4; ++jj) {
      int o = o0 + jj;
      float A  = rsqrtf(mv0[o] + 1e-3f) * g0[o];
      float Bc = b0[o] - mm0[o] * A;
      float4 y;
      y.x = fmaxf(fmaf(acc[jj][0], A, Bc), 0.0f);
      y.y = fmaxf(fmaf(acc[jj][1], A, Bc), 0.0f);
      y.z = fmaxf(fmaf(acc[jj][2], A, Bc), 0.0f);
      y.w = fmaxf(fmaf(acc[jj][3], A, Bc), 0.0f);
      *(float4*)&a1[sg][o][k0] = y;
    }
  }
  __syncthreads();
  for (int i = tid; i < 64 * 64; i += 256) wbuf[i] = w1[i];
  __syncthreads();

  // ---- layer 2: 64 -> 64 (reads a1, writes a2 = xT region) ----
  {
    const int ot = t & 15, kt = t >> 4;
    const int o0 = ot * 4, k0 = kt * 4;
    float acc[4][4] = {};
    for (int c = 0; c < 64; ++c) {
      float4 xv = *(const float4*)&a1[sg][c][k0];
      float4 wq = *(const float4*)&wbuf[c * 64 + o0];
      float wv[4] = { wq.x, wq.y, wq.z, wq.w };
      float xs[4] = { xv.x, xv.y, xv.z, xv.w };
#pragma unroll
      for (int a = 0; a < 4; ++a)
#pragma unroll
        for (int k2 = 0; k2 < 4; ++k2)
          acc[a][k2] = fmaf(wv[a], xs[k2], acc[a][k2]);
    }
#pragma unroll
    for (int jj = 0; jj < 4; ++jj) {
      int o = o0 + jj;
      float A  = rsqrtf(mv1[o] + 1e-3f) * g1[o];
      float Bc = b1_[o] - mm1[o] * A;
      float4 y;
      y.x = fmaxf(fmaf(acc[jj][0], A, Bc), 0.0f);
      y.y = fmaxf(fmaf(acc[jj][1], A, Bc), 0.0f);
      y.z = fmaxf(fmaf(acc[jj][2], A, Bc), 0.0f);
      y.w = fmaxf(fmaf(acc[jj][3], A, Bc), 0.0f);
      *(float4*)&xT[sg][o][k0] = y;
    }
  }
  __syncthreads();
  for (int i = tid; i < 64 * 128; i += 256) wbuf[i] = w2[i];
  __syncthreads();

  // ---- layer 3: 64 -> 128, BN+ReLU folded into max over k ----
  float* pm = &a1[0][0][0];          // [2][128][4] partial maxima
  {
    const int ot = t & 31, kt = t >> 5;
    const int o0 = ot * 4, k0 = kt * 8;
    float acc[4][8] = {};
    for (int c = 0; c < 64; ++c) {
      float4 xa = *(const float4*)&xT[sg][c][k0];
      float4 xb = *(const float4*)&xT[sg][c][k0 + 4];
      float4 wq = *(const float4*)&wbuf[c * 128 + o0];
      float wv[4] = { wq.x, wq.y, wq.z, wq.w };
      float xs[8] = { xa.x, xa.y, xa.z, xa.w, xb.x, xb.y, xb.z, xb.w };
#pragma unroll
      for (int a = 0; a < 4; ++a)
#pragma unroll
        for (int k2 = 0; k2 < 8; ++k2)
          acc[a][k2] = fmaf(wv[a], xs[k2], acc[a][k2]);
    }
#pragma unroll
    for (int jj = 0; jj < 4; ++jj) {
      int o = o0 + jj;
      float A  = rsqrtf(mv2[o] + 1e-3f) * g2[o];
      float Bc = b2_[o] - mm2[o] * A;
      float m = 0.0f;                 // relu>=0: max(0, max_k bn) == max_k relu(bn)
#pragma unroll
      for (int kk = 0; kk < 8; ++kk)
        m = fmaxf(m, fmaf(acc[jj][kk], A, Bc));
      pm[((sg * 128 + o) << 2) + kt] = m;
    }
  }
  __syncthreads();
  {
    const int sg2 = tid >> 7, o = tid & 127;
    const int basep = (sg2 * 128 + o) << 2;
    float m = fmaxf(fmaxf(pm[basep + 0], pm[basep + 1]),
                    fmaxf(pm[basep + 2], pm[basep + 3]));
    out1[(size_t)(BS0 + sg2) * 128 + o] = m;
  }
}

extern "C" void kernel_launch(void* const* d_in, const int* in_sizes, int n_in,
                              void* d_out, int out_size, void* d_ws, size_t ws_size,
                              hipStream_t stream) {
  const float* xyz    = (const float*)d_in[0];
  const float* points = (const float*)d_in[1];
  const float* w0  = (const float*)d_in[2];
  const float* g0  = (const float*)d_in[3];
  const float* b0  = (const float*)d_in[4];
  const float* mm0 = (const float*)d_in[5];
  const float* mv0 = (const float*)d_in[6];
  const float* w1  = (const float*)d_in[7];
  const float* g1  = (const float*)d_in[8];
  const float* b1  = (const float*)d_in[9];
  const float* mm1 = (const float*)d_in[10];
  const float* mv1 = (const float*)d_in[11];
  const float* w2  = (const float*)d_in[12];
  const float* g2  = (const float*)d_in[13];
  const float* b2  = (const float*)d_in[14];
  const float* mm2 = (const float*)d_in[15];
  const float* mv2 = (const float*)d_in[16];

  float* out      = (float*)d_out;                       // new_xyz f32[12288]
  float* out_pts  = out + (size_t)4 * 1024 * 3;          // new_points f32[524288]
  int*   knn      = (int*)d_ws;                          // 4*1024*32 int32

  fps_kernel<<<4, 1024, 0, stream>>>(xyz, out);
  knn_kernel<<<4096, 256, 0, stream>>>(xyz, out, knn);
  mlp_kernel<<<2048, 256, 0, stream>>>(xyz, points, out, knn,
      w0, g0, b0, mm0, mv0, w1, g1, b1, mm1, mv1, w2, g2, b2, mm2, mv2,
      out_pts);
}

// Round 3
// 2058.262 us; speedup vs baseline: 1.0600x; 1.0600x over previous
//
#include <hip/hip_runtime.h>
#include <hip/hip_bf16.h>
#include <stdint.h>

#define N_PTS 16384
#define S_OUT 1024

// Inputs: float32. Outputs: float32.
// d_out = new_xyz f32[4*1024*3] ++ new_points f32[4*1024*128].
// d_ws  = knn indices int32[4*1024*32].
//
// sq-formula fingerprints vs harness np ref (output-1 absmax):
//   (sumq - 2*dot) + sumx, dot in {asc,desc} x {mul/add,FMA}: 0.19921875 (all)
//   true distance (f32-direct == f64-direct): 0.3359375
//   knn: classic PointNet square_distance association —
//   sq = (sumq + sumx) - 2*dot, dot = ascending FMA (np.matmul/BLAS k=3
//   micro-kernel: acc=rn(a0*b0); acc=fma(a1,b1,acc); acc=fma(a2,b2,acc)).

// ---------------------------------------------------------------------------
// Kernel 1: farthest point sampling (bit-exact vs np ref).
// Distance math UNCHANGED: f32 direct, mul/add ascending, fminf.
// ROUND 14: register-budget arithmetic, done right this time.
//  R12/R13 evidence: block geometry SETS the budget. 1024-thr block => 4
//  waves/SIMD structural => 128 regs/wave hard cap => arrays in AGPRs =>
//  ~24 VALU ops/pt (accvgpr round-trips) instead of 12.
//  - 512 thr x 32 pts: arrays = 128 regs + ~40 working <= 256 arch VGPRs;
//    8-wave block needs only 2 waves/SIMD structurally.
//  - amdgpu_waves_per_eu(2,2) PINS occupancy (launch_bounds' 2nd arg is
//    only a min — R12 showed the allocator takes 4 waves/EU if allowed).
//  - argmax select chain split into 4 independent sub-chains (contiguous
//    8-pt ranges) merged ascending with strict '>': identical tie
//    semantics (lowest index on ties), 4x shallower dependency.
//  - 8 waves: 1 barrier/iter (double-buffered sred), lane-parallel block
//    reduce: every lane reads sred[lane&7], 3-step shfl_xor u64 butterfly.
// ---------------------------------------------------------------------------
__global__ __launch_bounds__(512)
__attribute__((amdgpu_waves_per_eu(2, 2)))
void fps_kernel(
    const float* __restrict__ xyz,
    float* __restrict__ out_newxyz)
{
  const int b    = blockIdx.x;
  const int tid  = threadIdx.x;
  const int lane = tid & 63;
  const int wid  = tid >> 6;           // 8 waves
  const float* base = xyz + (size_t)b * N_PTS * 3;

  float px[32], py[32], pz[32], dist[32];
#pragma unroll
  for (int i = 0; i < 32; ++i) {
    int n = tid * 32 + i;
    px[i] = base[n * 3 + 0];
    py[i] = base[n * 3 + 1];
    pz[i] = base[n * 3 + 2];
    dist[i] = 1e10f;
  }

  __shared__ unsigned long long sred[2][8];

  float cx = base[0], cy = base[1], cz = base[2];

  for (int s = 0; s < S_OUT; ++s) {
    if (tid == 0) {
      size_t o = ((size_t)b * S_OUT + s) * 3;
      out_newxyz[o + 0] = cx;
      out_newxyz[o + 1] = cy;
      out_newxyz[o + 2] = cz;
    }
    if (s == S_OUT - 1) break;

    // ---- update distances; argmax in 4 independent sub-chains ----
    float best[4]  = { -1.0f, -1.0f, -1.0f, -1.0f };
    int   bestI[4] = { 0, 0, 0, 0 };
#pragma unroll
    for (int i = 0; i < 32; ++i) {
      const int g = i >> 3;            // static after unroll
      float dx = __fsub_rn(px[i], cx);
      float dy = __fsub_rn(py[i], cy);
      float dz = __fsub_rn(pz[i], cz);
      float dd = __fadd_rn(__fadd_rn(__fmul_rn(dx, dx), __fmul_rn(dy, dy)),
                           __fmul_rn(dz, dz));
      float dm = fminf(dist[i], dd);
      dist[i] = dm;
      bool c = dm > best[g];           // strict: lowest index kept on ties
      best[g]  = c ? dm : best[g];
      bestI[g] = c ? i  : bestI[g];
    }
    // merge sub-chains ascending: strict '>' keeps earliest (lowest index)
    float bb = best[0]; int bi = bestI[0];
#pragma unroll
    for (int g = 1; g < 4; ++g) {
      bool c = best[g] > bb;
      bb = c ? best[g]  : bb;
      bi = c ? bestI[g] : bi;
    }
    const unsigned bestN = (unsigned)(tid * 32 + bi);

    // ---- wave reduce: f32 max butterfly, winner lane via ballot ----
    // lanes own ascending index blocks -> lowest lane == lowest index
    float m = bb;
#pragma unroll
    for (int off = 1; off < 64; off <<= 1)
      m = fmaxf(m, __shfl_xor(m, off));
    unsigned long long msk = __ballot(bb == m);
    int wl = __ffsll(msk) - 1;
    unsigned wn = (unsigned)__shfl((int)bestN, wl);

    const int p = s & 1;               // double buffer: 1 barrier/iter
    if (lane == 0)
      sred[p][wid] = ((unsigned long long)__float_as_uint(m) << 32) |
                     (unsigned long long)(0xFFFFFFFFu - wn);
    __syncthreads();

    // ---- block reduce: lane-parallel butterfly over 8 wave keys ----
    unsigned long long k = sred[p][lane & 7];
#pragma unroll
    for (int off = 1; off < 8; off <<= 1) {
      unsigned long long o = __shfl_xor(k, off);
      if (o > k) k = o;
    }
    unsigned n = 0xFFFFFFFFu - (unsigned)(k & 0xFFFFFFFFull);
    n = __builtin_amdgcn_readfirstlane(n);
    const float* pc = base + (size_t)n * 3;
    cx = pc[0]; cy = pc[1]; cz = pc[2];
  }
}

// ---------------------------------------------------------------------------
// Kernel 2: exact 32-NN per centroid, two-level radix select. (UNCHANGED)
//   sq = (sumq + sumx) - 2*dot,  dot = ascending FMA (BLAS sgemm k=3).
// sumq/sumx stay mul/add ascending (np.sum ufunc, n=3 sequential).
// Keys: sign-aware order-preserving u32. Levels bits[31:21], [20:10];
// candidates (u<<32)|n; stable (key, idx) extraction.
// ---------------------------------------------------------------------------
__global__ __launch_bounds__(256, 2) void knn_kernel(
    const float* __restrict__ xyz,
    const float* __restrict__ newxyz,
    int* __restrict__ knn_out)
{
  const int bs  = blockIdx.x;        // b*1024 + s
  const int b   = bs >> 10;
  const int tid = threadIdx.x;
  const float* base = xyz + (size_t)b * N_PTS * 3;

  const float qx = newxyz[(size_t)bs * 3 + 0];
  const float qy = newxyz[(size_t)bs * 3 + 1];
  const float qz = newxyz[(size_t)bs * 3 + 2];
  const float sumq = __fadd_rn(__fadd_rn(__fmul_rn(qx, qx), __fmul_rn(qy, qy)),
                               __fmul_rn(qz, qz));

  __shared__ unsigned hist[2048];
  __shared__ unsigned tsum[256];
  __shared__ unsigned long long cand[512];
  __shared__ unsigned long long s_min;
  __shared__ int s_b1, s_r1, s_b2, s_r2, s_cntL, s_cntC;

  for (int i = tid; i < 2048; i += 256) hist[i] = 0;
  if (tid == 0) { s_cntL = 0; s_cntC = 0; }
  __syncthreads();

#define KNN_KEY(n, u)                                                          \
    float x = base[(n) * 3 + 0];                                               \
    float y = base[(n) * 3 + 1];                                               \
    float z = base[(n) * 3 + 2];                                               \
    float sumx = __fadd_rn(__fadd_rn(__fmul_rn(x, x), __fmul_rn(y, y)),        \
                           __fmul_rn(z, z));                                   \
    float dot  = __fmul_rn(qx, x);                                             \
    dot = fmaf(qy, y, dot);                                                    \
    dot = fmaf(qz, z, dot);                                                    \
    float sq   = __fsub_rn(__fadd_rn(sumq, sumx), __fmul_rn(2.0f, dot));       \
    unsigned u = __float_as_uint(sq);                                          \
    u ^= (u & 0x80000000u) ? 0xFFFFFFFFu : 0x80000000u;

  // pass 1: level-1 histogram (bits 31:21)
  for (int j = 0; j < 64; ++j) {
    int n = j * 256 + tid;
    KNN_KEY(n, u)
    atomicAdd(&hist[u >> 21], 1u);
  }
  __syncthreads();

  unsigned ts = 0;
#pragma unroll
  for (int u = 0; u < 8; ++u) ts += hist[tid * 8 + u];
  tsum[tid] = ts;
  __syncthreads();

  if (tid == 0) {       // find level-1 bin containing rank 32
    unsigned acc = 0; int t2 = 0;
    for (; t2 < 256; ++t2) { unsigned h = tsum[t2]; if (acc + h >= 32u) break; acc += h; }
    int u2 = t2 * 8;
    for (;; ++u2) { unsigned h = hist[u2]; if (acc + h >= 32u) break; acc += h; }
    s_b1 = u2; s_r1 = 32 - (int)acc;      // rank within bin b1, >= 1
  }
  __syncthreads();
  const unsigned b1 = (unsigned)s_b1;
  const int r1 = s_r1;

  // clear histogram for level 2
  for (int i = tid; i < 2048; i += 256) hist[i] = 0;
  __syncthreads();

  // pass 2: level-2 histogram (bits 20:10) of keys inside bin b1
  for (int j = 0; j < 64; ++j) {
    int n = j * 256 + tid;
    KNN_KEY(n, u)
    if ((u >> 21) == b1) atomicAdd(&hist[(u >> 10) & 0x7FFu], 1u);
  }
  __syncthreads();

  ts = 0;
#pragma unroll
  for (int u = 0; u < 8; ++u) ts += hist[tid * 8 + u];
  tsum[tid] = ts;
  __syncthreads();

  if (tid == 0) {       // find level-2 sub-bin containing rank r1
    unsigned acc = 0; int t2 = 0;
    for (; t2 < 256; ++t2) { unsigned h = tsum[t2]; if (acc + h >= (unsigned)r1) break; acc += h; }
    int u2 = t2 * 8;
    for (;; ++u2) { unsigned h = hist[u2]; if (acc + h >= (unsigned)r1) break; acc += h; }
    s_b2 = u2; s_r2 = r1 - (int)acc;      // rank within sub-bin b2, >= 1
  }
  __syncthreads();
  const unsigned b2 = (unsigned)s_b2;

  int* outp = knn_out + (size_t)bs * 32;

  // pass 3: emit below-(b1,b2) directly; exact 22-bit-prefix matches -> cand
  for (int j = 0; j < 64; ++j) {
    int n = j * 256 + tid;
    KNN_KEY(n, u)
    unsigned bin = u >> 21;
    if (bin < b1) {
      int p = atomicAdd(&s_cntL, 1);
      outp[p] = n;
    } else if (bin == b1) {
      unsigned sub = (u >> 10) & 0x7FFu;
      if (sub < b2) {
        int p = atomicAdd(&s_cntL, 1);
        outp[p] = n;
      } else if (sub == b2) {
        int p = atomicAdd(&s_cntC, 1);
        if (p < 512) cand[p] = ((unsigned long long)u << 32) | (unsigned)n;
      }
    }
  }
  __syncthreads();
#undef KNN_KEY

  const int r   = s_r2;
  const int cl  = s_cntL;             // == 32 - r
  const int cnt = min(s_cntC, 512);
  unsigned long long last = 0ull;
  for (int i = 0; i < r; ++i) {
    if (tid == 0) s_min = ~0ull;
    __syncthreads();
    for (int p = tid; p < cnt; p += 256) {
      unsigned long long v = cand[p];
      if (i == 0 ? 1 : (v > last)) atomicMin(&s_min, v);
    }
    __syncthreads();
    unsigned long long m = s_min;
    if (tid == 0) outp[cl + i] = (int)(unsigned)(m & 0xFFFFFFFFull);
    last = m;
    __syncthreads();
  }
}

// ---------------------------------------------------------------------------
// Kernel 3: fused gather + (dense+BN+ReLU)x3 + max over K. 2 centroids per
// block (256 threads = 2 groups x 128). All f32; weights staged per-layer in
// LDS. Gathered indices clamped to [0,16383] defensively. (UNCHANGED)
// ---------------------------------------------------------------------------
__global__ __launch_bounds__(256, 2) void mlp_kernel(
    const float* __restrict__ xyz,
    const float* __restrict__ points,
    const float* __restrict__ newxyz,
    const int* __restrict__ knn,
    const float* __restrict__ w0, const float* __restrict__ g0,
    const float* __restrict__ b0, const float* __restrict__ mm0,
    const float* __restrict__ mv0,
    const float* __restrict__ w1, const float* __restrict__ g1,
    const float* __restrict__ b1_, const float* __restrict__ mm1,
    const float* __restrict__ mv1,
    const float* __restrict__ w2, const float* __restrict__ g2,
    const float* __restrict__ b2_, const float* __restrict__ mm2,
    const float* __restrict__ mv2,
    float* __restrict__ out1)
{
  const int tid = threadIdx.x;
  const int BS0 = blockIdx.x * 2;

  __shared__ __align__(16) float xT[2][67][36];  // input feats (c-major); reused as a2
  __shared__ __align__(16) float a1[2][64][36];  // layer-1 out; reused as k-max partials
  __shared__ __align__(16) float wbuf[8192];     // current layer weights (f32)

  // ---- gather: x = [grouped_xyz - new_xyz (3) ; grouped_points (64)] ----
  {
    const int sg = tid >> 7;
    const int j  = (tid >> 2) & 31;
    const int cq = tid & 3;
    const int S  = BS0 + sg;
    const int bb = S >> 10;
    const int n  = knn[(size_t)S * 32 + j] & (N_PTS - 1);   // defensive clamp
    const float* pbase = points + ((size_t)bb * N_PTS + n) * 64;
    const float* xbase = xyz + ((size_t)bb * N_PTS + n) * 3;
    for (int c = cq; c < 67; c += 4) {
      float v;
      if (c < 3) v = __fsub_rn(xbase[c], newxyz[(size_t)S * 3 + c]);
      else       v = pbase[c - 3];
      xT[sg][c][j] = v;
    }
  }
  for (int i = tid; i < 67 * 64; i += 256) wbuf[i] = w0[i];
  __syncthreads();

  const int sg = tid >> 7;
  const int t  = tid & 127;

  // ---- layer 1: 67 -> 64 ----
  {
    const int ot = t & 15, kt = t >> 4;
    const int o0 = ot * 4, k0 = kt * 4;
    float acc[4][4] = {};
    for (int c = 0; c < 67; ++c) {
      float4 xv = *(const float4*)&xT[sg][c][k0];
      float4 wq = *(const float4*)&wbuf[c * 64 + o0];
      float wv[4] = { wq.x, wq.y, wq.z, wq.w };
      float xs[4] = { xv.x, xv.y, xv.z, xv.w };
#pragma unroll
      for (int a = 0; a < 4; ++a)
#pragma unroll
        for (int k2 = 0; k2 < 4; ++k2)
          acc[a][k2] = fmaf(wv[a], xs[k2], acc[a][k2]);
    }
#pragma unroll
    for (int jj = 0; jj < 4; ++jj) {
      int o = o0 + jj;
      float A  = rsqrtf(mv0[o] + 1e-3f) * g0[o];
      float Bc = b0[o] - mm0[o] * A;
      float4 y;
      y.x = fmaxf(fmaf(acc[jj][0], A, Bc), 0.0f);
      y.y = fmaxf(fmaf(acc[jj][1], A, Bc), 0.0f);
      y.z = fmaxf(fmaf(acc[jj][2], A, Bc), 0.0f);
      y.w = fmaxf(fmaf(acc[jj][3], A, Bc), 0.0f);
      *(float4*)&a1[sg][o][k0] = y;
    }
  }
  __syncthreads();
  for (int i = tid; i < 64 * 64; i += 256) wbuf[i] = w1[i];
  __syncthreads();

  // ---- layer 2: 64 -> 64 (reads a1, writes a2 = xT region) ----
  {
    const int ot = t & 15, kt = t >> 4;
    const int o0 = ot * 4, k0 = kt * 4;
    float acc[4][4] = {};
    for (int c = 0; c < 64; ++c) {
      float4 xv = *(const float4*)&a1[sg][c][k0];
      float4 wq = *(const float4*)&wbuf[c * 64 + o0];
      float wv[4] = { wq.x, wq.y, wq.z, wq.w };
      float xs[4] = { xv.x, xv.y, xv.z, xv.w };
#pragma unroll
      for (int a = 0; a < 4; ++a)
#pragma unroll
        for (int k2 = 0; k2 < 4; ++k2)
          acc[a][k2] = fmaf(wv[a], xs[k2], acc[a][k2]);
    }
#pragma unroll
    for (int jj = 0; jj < 4; ++jj) {
      int o = o0 + jj;
      float A  = rsqrtf(mv1[o] + 1e-3f) * g1[o];
      float Bc = b1_[o] - mm1[o] * A;
      float4 y;
      y.x = fmaxf(fmaf(acc[jj][0], A, Bc), 0.0f);
      y.y = fmaxf(fmaf(acc[jj][1], A, Bc), 0.0f);
      y.z = fmaxf(fmaf(acc[jj][2], A, Bc), 0.0f);
      y.w = fmaxf(fmaf(acc[jj][3], A, Bc), 0.0f);
      *(float4*)&xT[sg][o][k0] = y;
    }
  }
  __syncthreads();
  for (int i = tid; i < 64 * 128; i += 256) wbuf[i] = w2[i];
  __syncthreads();

  // ---- layer 3: 64 -> 128, BN+ReLU folded into max over k ----
  float* pm = &a1[0][0][0];          // [2][128][4] partial maxima
  {
    const int ot = t & 31, kt = t >> 5;
    const int o0 = ot * 4, k0 = kt * 8;
    float acc[4][8] = {};
    for (int c = 0; c < 64; ++c) {
      float4 xa = *(const float4*)&xT[sg][c][k0];
      float4 xb = *(const float4*)&xT[sg][c][k0 + 4];
      float4 wq = *(const float4*)&wbuf[c * 128 + o0];
      float wv[4] = { wq.x, wq.y, wq.z, wq.w };
      float xs[8] = { xa.x, xa.y, xa.z, xa.w, xb.x, xb.y, xb.z, xb.w };
#pragma unroll
      for (int a = 0; a < 4; ++a)
#pragma unroll
        for (int k2 = 0; k2 < 8; ++k2)
          acc[a][k2] = fmaf(wv[a], xs[k2], acc[a][k2]);
    }
#pragma unroll
    for (int jj = 0; jj < 4; ++jj) {
      int o = o0 + jj;
      float A  = rsqrtf(mv2[o] + 1e-3f) * g2[o];
      float Bc = b2_[o] - mm2[o] * A;
      float m = 0.0f;                 // relu>=0: max(0, max_k bn) == max_k relu(bn)
#pragma unroll
      for (int kk = 0; kk < 8; ++kk)
        m = fmaxf(m, fmaf(acc[jj][kk], A, Bc));
      pm[((sg * 128 + o) << 2) + kt] = m;
    }
  }
  __syncthreads();
  {
    const int sg2 = tid >> 7, o = tid & 127;
    const int basep = (sg2 * 128 + o) << 2;
    float m = fmaxf(fmaxf(pm[basep + 0], pm[basep + 1]),
                    fmaxf(pm[basep + 2], pm[basep + 3]));
    out1[(size_t)(BS0 + sg2) * 128 + o] = m;
  }
}

extern "C" void kernel_launch(void* const* d_in, const int* in_sizes, int n_in,
                              void* d_out, int out_size, void* d_ws, size_t ws_size,
                              hipStream_t stream) {
  const float* xyz    = (const float*)d_in[0];
  const float* points = (const float*)d_in[1];
  const float* w0  = (const float*)d_in[2];
  const float* g0  = (const float*)d_in[3];
  const float* b0  = (const float*)d_in[4];
  const float* mm0 = (const float*)d_in[5];
  const float* mv0 = (const float*)d_in[6];
  const float* w1  = (const float*)d_in[7];
  const float* g1  = (const float*)d_in[8];
  const float* b1  = (const float*)d_in[9];
  const float* mm1 = (const float*)d_in[10];
  const float* mv1 = (const float*)d_in[11];
  const float* w2  = (const float*)d_in[12];
  const float* g2  = (const float*)d_in[13];
  const float* b2  = (const float*)d_in[14];
  const float* mm2 = (const float*)d_in[15];
  const float* mv2 = (const float*)d_in[16];

  float* out      = (float*)d_out;                       // new_xyz f32[12288]
  float* out_pts  = out + (size_t)4 * 1024 * 3;          // new_points f32[524288]
  int*   knn      = (int*)d_ws;                          // 4*1024*32 int32

  fps_kernel<<<4, 512, 0, stream>>>(xyz, out);
  knn_kernel<<<4096, 256, 0, stream>>>(xyz, out, knn);
  mlp_kernel<<<2048, 256, 0, stream>>>(xyz, points, out, knn,
      w0, g0, b0, mm0, mv0, w1, g1, b1, mm1, mv1, w2, g2, b2, mm2, mv2,
      out_pts);
}

// Round 4
// 1962.275 us; speedup vs baseline: 1.1118x; 1.0489x over previous
//
#include <hip/hip_runtime.h>
#include <hip/hip_bf16.h>
#include <stdint.h>

#define N_PTS 16384
#define S_OUT 1024

// Inputs: float32. Outputs: float32.
// d_out = new_xyz f32[4*1024*3] ++ new_points f32[4*1024*128].
// d_ws  = knn indices int32[4*1024*32].
//
// sq-formula fingerprints vs harness np ref (output-1 absmax):
//   (sumq - 2*dot) + sumx, dot in {asc,desc} x {mul/add,FMA}: 0.19921875 (all)
//   true distance (f32-direct == f64-direct): 0.3359375
//   knn: classic PointNet square_distance association —
//   sq = (sumq + sumx) - 2*dot, dot = ascending FMA (np.matmul/BLAS k=3
//   micro-kernel: acc=rn(a0*b0); acc=fma(a1,b1,acc); acc=fma(a2,b2,acc)).

typedef float v2f __attribute__((ext_vector_type(2)));

// ---------------------------------------------------------------------------
// Kernel 1: farthest point sampling (bit-exact vs np ref).
// Distance math UNCHANGED per component: f32, mul/add ascending, min.
// ROUND 15: stop fighting the AGPR allocator; cut ops + tail instead.
//  R12-R14 evidence: allocator AGPR-homes the 128-float arrays regardless
//  of launch_bounds/waves_per_eu (VGPR_Count 80/48/88); measured ~22
//  VALU ops/pt vs 12 source ops.
//  - float2 packed pairs -> v_pk_add/mul_f32: ~1 inst per 2 pts for
//    sub/mul/add; AGPR-move tax also halves per op (b64 values).
//  - fp contract(off) pragma: HIP defaults to contract=fast; plain
//    operators would fuse mul+add -> pk_fma and break bit-exactness.
//  - value-only argmax: per-point index tracking (cmp+2 cndmask) removed.
//    Block max M via max3 chains + f32 wave butterfly + 8-float LDS merge.
//    Index recovered AFTER: only threads with local max == M (usually 1)
//    scan their 32 dists descending (bi=(d==M)?j:bi keeps lowest j) and
//    atomicMin the global index. fmax/atomicMin preserve np.argmax
//    semantics exactly: max bit pattern exact (finite, >= +0), lowest
//    index on ties.
//  - 2 barriers/iter (value merge; index publish), double-buffered LDS.
// ---------------------------------------------------------------------------
__global__ __launch_bounds__(512)
__attribute__((amdgpu_waves_per_eu(2, 2)))
void fps_kernel(
    const float* __restrict__ xyz,
    float* __restrict__ out_newxyz)
{
#pragma clang fp contract(off)
  const int b    = blockIdx.x;
  const int tid  = threadIdx.x;
  const int lane = tid & 63;
  const int wid  = tid >> 6;           // 8 waves
  const float* base = xyz + (size_t)b * N_PTS * 3;

  v2f px[16], py[16], pz[16], dist[16];
#pragma unroll
  for (int i = 0; i < 16; ++i) {
    int n0 = (tid * 32 + 2 * i) * 3;
    px[i] = (v2f){ base[n0 + 0], base[n0 + 3] };
    py[i] = (v2f){ base[n0 + 1], base[n0 + 4] };
    pz[i] = (v2f){ base[n0 + 2], base[n0 + 5] };
    dist[i] = (v2f){ 1e10f, 1e10f };
  }

  __shared__ float swave[2][8];
  __shared__ unsigned s_idx[2];

  if (tid == 0) { s_idx[0] = 0xFFFFFFFFu; s_idx[1] = 0xFFFFFFFFu; }

  float cx = base[0], cy = base[1], cz = base[2];

  for (int s = 0; s < S_OUT; ++s) {
    if (tid == 0) {
      size_t o = ((size_t)b * S_OUT + s) * 3;
      out_newxyz[o + 0] = cx;
      out_newxyz[o + 1] = cy;
      out_newxyz[o + 2] = cz;
    }
    if (s == S_OUT - 1) break;

    const v2f cx2 = (v2f){ cx, cx };
    const v2f cy2 = (v2f){ cy, cy };
    const v2f cz2 = (v2f){ cz, cz };

    // ---- distance update (packed pairs) + value-only max chains ----
    float m0 = -1.0f, m1 = -1.0f, m2 = -1.0f, m3 = -1.0f;
#pragma unroll
    for (int i = 0; i < 16; ++i) {
      v2f dx = px[i] - cx2;
      v2f dy = py[i] - cy2;
      v2f dz = pz[i] - cz2;
      v2f dd = (dx * dx + dy * dy) + dz * dz;   // contract OFF: mul/add exact
      v2f dm = __builtin_elementwise_min(dist[i], dd);
      dist[i] = dm;
      // fmaxf(fmaxf(a,b),c) folds to v_max3_f32; 4 independent chains
      if ((i & 3) == 0)      m0 = fmaxf(fmaxf(m0, dm.x), dm.y);
      else if ((i & 3) == 1) m1 = fmaxf(fmaxf(m1, dm.x), dm.y);
      else if ((i & 3) == 2) m2 = fmaxf(fmaxf(m2, dm.x), dm.y);
      else                   m3 = fmaxf(fmaxf(m3, dm.x), dm.y);
    }
    const float lm = fmaxf(fmaxf(m0, m1), fmaxf(m2, m3));

    // ---- wave reduce (value only, f32 butterfly) ----
    float wm = lm;
#pragma unroll
    for (int off = 1; off < 64; off <<= 1)
      wm = fmaxf(wm, __shfl_xor(wm, off));

    const int p = s & 1;
    if (lane == 0) swave[p][wid] = wm;
    __syncthreads();

    // ---- block max: all threads merge the 8 wave maxima (max3 tree) ----
    float M = swave[p][0];
    {
      float a = fmaxf(fmaxf(swave[p][1], swave[p][2]), swave[p][3]);
      float c = fmaxf(fmaxf(swave[p][4], swave[p][5]), swave[p][6]);
      M = fmaxf(fmaxf(M, swave[p][7]), fmaxf(a, c));
    }

    // ---- index find: only local-max==M threads scan (usually 1) ----
    if (lm == M) {
      int bi = 0;
#pragma unroll
      for (int j = 31; j >= 0; --j) {         // descending: keep lowest j
        float d = dist[j >> 1][j & 1];
        bi = (d == M) ? j : bi;
      }
      atomicMin(&s_idx[p], (unsigned)(tid * 32 + bi));
    }
    if (tid == 0) s_idx[p ^ 1] = 0xFFFFFFFFu;  // reset other buffer
    __syncthreads();

    unsigned n = s_idx[p];
    n = __builtin_amdgcn_readfirstlane(n);
    const float* pc = base + (size_t)n * 3;
    cx = pc[0]; cy = pc[1]; cz = pc[2];
  }
}

// ---------------------------------------------------------------------------
// Kernel 2: exact 32-NN per centroid, two-level radix select. (UNCHANGED)
//   sq = (sumq + sumx) - 2*dot,  dot = ascending FMA (BLAS sgemm k=3).
// sumq/sumx stay mul/add ascending (np.sum ufunc, n=3 sequential).
// Keys: sign-aware order-preserving u32. Levels bits[31:21], [20:10];
// candidates (u<<32)|n; stable (key, idx) extraction.
// ---------------------------------------------------------------------------
__global__ __launch_bounds__(256, 2) void knn_kernel(
    const float* __restrict__ xyz,
    const float* __restrict__ newxyz,
    int* __restrict__ knn_out)
{
  const int bs  = blockIdx.x;        // b*1024 + s
  const int b   = bs >> 10;
  const int tid = threadIdx.x;
  const float* base = xyz + (size_t)b * N_PTS * 3;

  const float qx = newxyz[(size_t)bs * 3 + 0];
  const float qy = newxyz[(size_t)bs * 3 + 1];
  const float qz = newxyz[(size_t)bs * 3 + 2];
  const float sumq = __fadd_rn(__fadd_rn(__fmul_rn(qx, qx), __fmul_rn(qy, qy)),
                               __fmul_rn(qz, qz));

  __shared__ unsigned hist[2048];
  __shared__ unsigned tsum[256];
  __shared__ unsigned long long cand[512];
  __shared__ unsigned long long s_min;
  __shared__ int s_b1, s_r1, s_b2, s_r2, s_cntL, s_cntC;

  for (int i = tid; i < 2048; i += 256) hist[i] = 0;
  if (tid == 0) { s_cntL = 0; s_cntC = 0; }
  __syncthreads();

#define KNN_KEY(n, u)                                                          \
    float x = base[(n) * 3 + 0];                                               \
    float y = base[(n) * 3 + 1];                                               \
    float z = base[(n) * 3 + 2];                                               \
    float sumx = __fadd_rn(__fadd_rn(__fmul_rn(x, x), __fmul_rn(y, y)),        \
                           __fmul_rn(z, z));                                   \
    float dot  = __fmul_rn(qx, x);                                             \
    dot = fmaf(qy, y, dot);                                                    \
    dot = fmaf(qz, z, dot);                                                    \
    float sq   = __fsub_rn(__fadd_rn(sumq, sumx), __fmul_rn(2.0f, dot));       \
    unsigned u = __float_as_uint(sq);                                          \
    u ^= (u & 0x80000000u) ? 0xFFFFFFFFu : 0x80000000u;

  // pass 1: level-1 histogram (bits 31:21)
  for (int j = 0; j < 64; ++j) {
    int n = j * 256 + tid;
    KNN_KEY(n, u)
    atomicAdd(&hist[u >> 21], 1u);
  }
  __syncthreads();

  unsigned ts = 0;
#pragma unroll
  for (int u = 0; u < 8; ++u) ts += hist[tid * 8 + u];
  tsum[tid] = ts;
  __syncthreads();

  if (tid == 0) {       // find level-1 bin containing rank 32
    unsigned acc = 0; int t2 = 0;
    for (; t2 < 256; ++t2) { unsigned h = tsum[t2]; if (acc + h >= 32u) break; acc += h; }
    int u2 = t2 * 8;
    for (;; ++u2) { unsigned h = hist[u2]; if (acc + h >= 32u) break; acc += h; }
    s_b1 = u2; s_r1 = 32 - (int)acc;      // rank within bin b1, >= 1
  }
  __syncthreads();
  const unsigned b1 = (unsigned)s_b1;
  const int r1 = s_r1;

  // clear histogram for level 2
  for (int i = tid; i < 2048; i += 256) hist[i] = 0;
  __syncthreads();

  // pass 2: level-2 histogram (bits 20:10) of keys inside bin b1
  for (int j = 0; j < 64; ++j) {
    int n = j * 256 + tid;
    KNN_KEY(n, u)
    if ((u >> 21) == b1) atomicAdd(&hist[(u >> 10) & 0x7FFu], 1u);
  }
  __syncthreads();

  ts = 0;
#pragma unroll
  for (int u = 0; u < 8; ++u) ts += hist[tid * 8 + u];
  tsum[tid] = ts;
  __syncthreads();

  if (tid == 0) {       // find level-2 sub-bin containing rank r1
    unsigned acc = 0; int t2 = 0;
    for (; t2 < 256; ++t2) { unsigned h = tsum[t2]; if (acc + h >= (unsigned)r1) break; acc += h; }
    int u2 = t2 * 8;
    for (;; ++u2) { unsigned h = hist[u2]; if (acc + h >= (unsigned)r1) break; acc += h; }
    s_b2 = u2; s_r2 = r1 - (int)acc;      // rank within sub-bin b2, >= 1
  }
  __syncthreads();
  const unsigned b2 = (unsigned)s_b2;

  int* outp = knn_out + (size_t)bs * 32;

  // pass 3: emit below-(b1,b2) directly; exact 22-bit-prefix matches -> cand
  for (int j = 0; j < 64; ++j) {
    int n = j * 256 + tid;
    KNN_KEY(n, u)
    unsigned bin = u >> 21;
    if (bin < b1) {
      int p = atomicAdd(&s_cntL, 1);
      outp[p] = n;
    } else if (bin == b1) {
      unsigned sub = (u >> 10) & 0x7FFu;
      if (sub < b2) {
        int p = atomicAdd(&s_cntL, 1);
        outp[p] = n;
      } else if (sub == b2) {
        int p = atomicAdd(&s_cntC, 1);
        if (p < 512) cand[p] = ((unsigned long long)u << 32) | (unsigned)n;
      }
    }
  }
  __syncthreads();
#undef KNN_KEY

  const int r   = s_r2;
  const int cl  = s_cntL;             // == 32 - r
  const int cnt = min(s_cntC, 512);
  unsigned long long last = 0ull;
  for (int i = 0; i < r; ++i) {
    if (tid == 0) s_min = ~0ull;
    __syncthreads();
    for (int p = tid; p < cnt; p += 256) {
      unsigned long long v = cand[p];
      if (i == 0 ? 1 : (v > last)) atomicMin(&s_min, v);
    }
    __syncthreads();
    unsigned long long m = s_min;
    if (tid == 0) outp[cl + i] = (int)(unsigned)(m & 0xFFFFFFFFull);
    last = m;
    __syncthreads();
  }
}

// ---------------------------------------------------------------------------
// Kernel 3: fused gather + (dense+BN+ReLU)x3 + max over K. 2 centroids per
// block (256 threads = 2 groups x 128). All f32; weights staged per-layer in
// LDS. Gathered indices clamped to [0,16383] defensively. (UNCHANGED)
// ---------------------------------------------------------------------------
__global__ __launch_bounds__(256, 2) void mlp_kernel(
    const float* __restrict__ xyz,
    const float* __restrict__ points,
    const float* __restrict__ newxyz,
    const int* __restrict__ knn,
    const float* __restrict__ w0, const float* __restrict__ g0,
    const float* __restrict__ b0, const float* __restrict__ mm0,
    const float* __restrict__ mv0,
    const float* __restrict__ w1, const float* __restrict__ g1,
    const float* __restrict__ b1_, const float* __restrict__ mm1,
    const float* __restrict__ mv1,
    const float* __restrict__ w2, const float* __restrict__ g2,
    const float* __restrict__ b2_, const float* __restrict__ mm2,
    const float* __restrict__ mv2,
    float* __restrict__ out1)
{
  const int tid = threadIdx.x;
  const int BS0 = blockIdx.x * 2;

  __shared__ __align__(16) float xT[2][67][36];  // input feats (c-major); reused as a2
  __shared__ __align__(16) float a1[2][64][36];  // layer-1 out; reused as k-max partials
  __shared__ __align__(16) float wbuf[8192];     // current layer weights (f32)

  // ---- gather: x = [grouped_xyz - new_xyz (3) ; grouped_points (64)] ----
  {
    const int sg = tid >> 7;
    const int j  = (tid >> 2) & 31;
    const int cq = tid & 3;
    const int S  = BS0 + sg;
    const int bb = S >> 10;
    const int n  = knn[(size_t)S * 32 + j] & (N_PTS - 1);   // defensive clamp
    const float* pbase = points + ((size_t)bb * N_PTS + n) * 64;
    const float* xbase = xyz + ((size_t)bb * N_PTS + n) * 3;
    for (int c = cq; c < 67; c += 4) {
      float v;
      if (c < 3) v = __fsub_rn(xbase[c], newxyz[(size_t)S * 3 + c]);
      else       v = pbase[c - 3];
      xT[sg][c][j] = v;
    }
  }
  for (int i = tid; i < 67 * 64; i += 256) wbuf[i] = w0[i];
  __syncthreads();

  const int sg = tid >> 7;
  const int t  = tid & 127;

  // ---- layer 1: 67 -> 64 ----
  {
    const int ot = t & 15, kt = t >> 4;
    const int o0 = ot * 4, k0 = kt * 4;
    float acc[4][4] = {};
    for (int c = 0; c < 67; ++c) {
      float4 xv = *(const float4*)&xT[sg][c][k0];
      float4 wq = *(const float4*)&wbuf[c * 64 + o0];
      float wv[4] = { wq.x, wq.y, wq.z, wq.w };
      float xs[4] = { xv.x, xv.y, xv.z, xv.w };
#pragma unroll
      for (int a = 0; a < 4; ++a)
#pragma unroll
        for (int k2 = 0; k2 < 4; ++k2)
          acc[a][k2] = fmaf(wv[a], xs[k2], acc[a][k2]);
    }
#pragma unroll
    for (int jj = 0; jj < 4; ++jj) {
      int o = o0 + jj;
      float A  = rsqrtf(mv0[o] + 1e-3f) * g0[o];
      float Bc = b0[o] - mm0[o] * A;
      float4 y;
      y.x = fmaxf(fmaf(acc[jj][0], A, Bc), 0.0f);
      y.y = fmaxf(fmaf(acc[jj][1], A, Bc), 0.0f);
      y.z = fmaxf(fmaf(acc[jj][2], A, Bc), 0.0f);
      y.w = fmaxf(fmaf(acc[jj][3], A, Bc), 0.0f);
      *(float4*)&a1[sg][o][k0] = y;
    }
  }
  __syncthreads();
  for (int i = tid; i < 64 * 64; i += 256) wbuf[i] = w1[i];
  __syncthreads();

  // ---- layer 2: 64 -> 64 (reads a1, writes a2 = xT region) ----
  {
    const int ot = t & 15, kt = t >> 4;
    const int o0 = ot * 4, k0 = kt * 4;
    float acc[4][4] = {};
    for (int c = 0; c < 64; ++c) {
      float4 xv = *(const float4*)&a1[sg][c][k0];
      float4 wq = *(const float4*)&wbuf[c * 64 + o0];
      float wv[4] = { wq.x, wq.y, wq.z, wq.w };
      float xs[4] = { xv.x, xv.y, xv.z, xv.w };
#pragma unroll
      for (int a = 0; a < 4; ++a)
#pragma unroll
        for (int k2 = 0; k2 < 4; ++k2)
          acc[a][k2] = fmaf(wv[a], xs[k2], acc[a][k2]);
    }
#pragma unroll
    for (int jj = 0; jj < 4; ++jj) {
      int o = o0 + jj;
      float A  = rsqrtf(mv1[o] + 1e-3f) * g1[o];
      float Bc = b1_[o] - mm1[o] * A;
      float4 y;
      y.x = fmaxf(fmaf(acc[jj][0], A, Bc), 0.0f);
      y.y = fmaxf(fmaf(acc[jj][1], A, Bc), 0.0f);
      y.z = fmaxf(fmaf(acc[jj][2], A, Bc), 0.0f);
      y.w = fmaxf(fmaf(acc[jj][3], A, Bc), 0.0f);
      *(float4*)&xT[sg][o][k0] = y;
    }
  }
  __syncthreads();
  for (int i = tid; i < 64 * 128; i += 256) wbuf[i] = w2[i];
  __syncthreads();

  // ---- layer 3: 64 -> 128, BN+ReLU folded into max over k ----
  float* pm = &a1[0][0][0];          // [2][128][4] partial maxima
  {
    const int ot = t & 31, kt = t >> 5;
    const int o0 = ot * 4, k0 = kt * 8;
    float acc[4][8] = {};
    for (int c = 0; c < 64; ++c) {
      float4 xa = *(const float4*)&xT[sg][c][k0];
      float4 xb = *(const float4*)&xT[sg][c][k0 + 4];
      float4 wq = *(const float4*)&wbuf[c * 128 + o0];
      float wv[4] = { wq.x, wq.y, wq.z, wq.w };
      float xs[8] = { xa.x, xa.y, xa.z, xa.w, xb.x, xb.y, xb.z, xb.w };
#pragma unroll
      for (int a = 0; a < 4; ++a)
#pragma unroll
        for (int k2 = 0; k2 < 8; ++k2)
          acc[a][k2] = fmaf(wv[a], xs[k2], acc[a][k2]);
    }
#pragma unroll
    for (int jj = 0; jj < 4; ++jj) {
      int o = o0 + jj;
      float A  = rsqrtf(mv2[o] + 1e-3f) * g2[o];
      float Bc = b2_[o] - mm2[o] * A;
      float m = 0.0f;                 // relu>=0: max(0, max_k bn) == max_k relu(bn)
#pragma unroll
      for (int kk = 0; kk < 8; ++kk)
        m = fmaxf(m, fmaf(acc[jj][kk], A, Bc));
      pm[((sg * 128 + o) << 2) + kt] = m;
    }
  }
  __syncthreads();
  {
    const int sg2 = tid >> 7, o = tid & 127;
    const int basep = (sg2 * 128 + o) << 2;
    float m = fmaxf(fmaxf(pm[basep + 0], pm[basep + 1]),
                    fmaxf(pm[basep + 2], pm[basep + 3]));
    out1[(size_t)(BS0 + sg2) * 128 + o] = m;
  }
}

extern "C" void kernel_launch(void* const* d_in, const int* in_sizes, int n_in,
                              void* d_out, int out_size, void* d_ws, size_t ws_size,
                              hipStream_t stream) {
  const float* xyz    = (const float*)d_in[0];
  const float* points = (const float*)d_in[1];
  const float* w0  = (const float*)d_in[2];
  const float* g0  = (const float*)d_in[3];
  const float* b0  = (const float*)d_in[4];
  const float* mm0 = (const float*)d_in[5];
  const float* mv0 = (const float*)d_in[6];
  const float* w1  = (const float*)d_in[7];
  const float* g1  = (const float*)d_in[8];
  const float* b1  = (const float*)d_in[9];
  const float* mm1 = (const float*)d_in[10];
  const float* mv1 = (const float*)d_in[11];
  const float* w2  = (const float*)d_in[12];
  const float* g2  = (const float*)d_in[13];
  const float* b2  = (const float*)d_in[14];
  const float* mm2 = (const float*)d_in[15];
  const float* mv2 = (const float*)d_in[16];

  float* out      = (float*)d_out;                       // new_xyz f32[12288]
  float* out_pts  = out + (size_t)4 * 1024 * 3;          // new_points f32[524288]
  int*   knn      = (int*)d_ws;                          // 4*1024*32 int32

  fps_kernel<<<4, 512, 0, stream>>>(xyz, out);
  knn_kernel<<<4096, 256, 0, stream>>>(xyz, out, knn);
  mlp_kernel<<<2048, 256, 0, stream>>>(xyz, points, out, knn,
      w0, g0, b0, mm0, mv0, w1, g1, b1, mm1, mv1, w2, g2, b2, mm2, mv2,
      out_pts);
}